// Round 9
// baseline (72.086 us; speedup 1.0000x reference)
//
#include <hip/hip_runtime.h>
#include <hip/hip_bf16.h>
#include <stdint.h>

#define B_  32
#define S_  4096
#define D_  64
#define DK_ 256

typedef float f32x4 __attribute__((ext_vector_type(4)));
typedef short s16x8 __attribute__((ext_vector_type(8)));
typedef uint32_t u32x4 __attribute__((ext_vector_type(4)));

static __device__ __forceinline__ uint16_t f2bf(float f) {
    union { float f; uint32_t u; } x; x.f = f;
    uint32_t u = x.u;
    u += 0x7FFFu + ((u >> 16) & 1u);   // RNE
    return (uint16_t)(u >> 16);
}

static __device__ __forceinline__ float bf2f(uint32_t hi16) {
    union { uint32_t u; float f; } x; x.u = hi16;
    return x.f;
}

static __device__ __forceinline__ uint32_t pk2(float a, float b) {
    __hip_bfloat162 h = __float22bfloat162_rn(float2{a, b});
    union { __hip_bfloat162 h; uint32_t u; } c; c.h = h;
    return c.u;
}

static __device__ __forceinline__ void gload_lds16(const uint16_t* g, uint16_t* l) {
    __builtin_amdgcn_global_load_lds(
        (const __attribute__((address_space(1))) uint32_t*)g,
        (__attribute__((address_space(3))) uint32_t*)l, 16, 0, 0);
}

// ---------------------------------------------------------------------------
// Pass A1: E_w fp32 -> bf16 (same [DK][S] layout, s contiguous).
// ---------------------------------------------------------------------------
__global__ __launch_bounds__(256) void ewcvt(const float* __restrict__ E_w,
                                             uint16_t* __restrict__ Ewb) {
    const int idx = (blockIdx.x * 256 + threadIdx.x) * 8;
    const float4 f0 = *(const float4*)(E_w + idx);
    const float4 f1 = *(const float4*)(E_w + idx + 4);
    s16x8 o;
    o[0] = (short)f2bf(f0.x); o[1] = (short)f2bf(f0.y);
    o[2] = (short)f2bf(f0.z); o[3] = (short)f2bf(f0.w);
    o[4] = (short)f2bf(f1.x); o[5] = (short)f2bf(f1.y);
    o[6] = (short)f2bf(f1.z); o[7] = (short)f2bf(f1.w);
    *(s16x8*)(Ewb + idx) = o;
}

// ---------------------------------------------------------------------------
// Pass B: projection GEMM. ss split = 16 (grid 1024 = 4 blocks/CU = 50% occ),
// 8 K-iterations, 2-phase double-buffer; bf16-pair partials in [d][kk] layout.
// part_u32[r][d][kkp]: r = (p*32+b)*16+ss, kkp = kk/2 (lo half = even kk).
// ---------------------------------------------------------------------------
__global__ __launch_bounds__(256) void proj_mfma(
        const uint16_t* __restrict__ Ewb,
        const float* __restrict__ kin, const float* __restrict__ vin,
        uint32_t* __restrict__ part) {
    const int bid = blockIdx.x;
    const int ss = bid & 15;
    const int b  = (bid >> 4) & 31;
    const int p  = bid >> 9;
    const float* x = (p ? vin : kin) + (size_t)b * S_ * D_;
    uint32_t* outp = part + ((size_t)((p*32 + b)*16 + ss)) * 8192;

    __shared__ __align__(16) uint16_t lds0[20 * 512];   // 20 KB
    __shared__ __align__(16) uint16_t lds1[20 * 512];   // 20 KB

    const int tid  = threadIdx.x;
    const int w    = tid >> 6;
    const int lane = tid & 63;
    const int l16  = lane & 15;
    const int grp  = lane >> 4;

    // A sources (bf16 E_w, k-contiguous): s-slice = ss*256 .. +255
    const int s0 = ss * 256 + grp * 8;
    const uint16_t* srcA[4];
    #pragma unroll
    for (int i = 0; i < 4; ++i)
        srcA[i] = Ewb + (size_t)((w*4 + i)*16 + l16) * S_ + s0;

    // B source (fp32 x, [s][d]): thread owns column d = tid&63, rows w*8..+7
    const int dcol = tid & 63;
    const float* srcB = x + ((size_t)(ss*256 + w*8)) * D_ + dcol;
    const int boff = 16*512 + (dcol >> 4)*512 + (w*16 + (dcol & 15))*8;

    f32x4 acc[4][4] = {};

    // ---- prologue: stage tile 0 into lds0
    {
        float xv[8];
        #pragma unroll
        for (int i = 0; i < 8; ++i) xv[i] = srcB[i * D_];
        #pragma unroll
        for (int i = 0; i < 4; ++i)
            gload_lds16(srcA[i], &lds0[(w*4 + i) * 512]);
        s16x8 h;
        #pragma unroll
        for (int i = 0; i < 8; ++i) h[i] = (short)f2bf(xv[i]);
        *(s16x8*)&lds0[boff] = h;
    }
    __syncthreads();

    // ---- 2-phase main loop: STAGE(t+1) issued before compute(t)
    #pragma unroll
    for (int t = 0; t < 8; ++t) {
        uint16_t* cur = (t & 1) ? lds1 : lds0;
        uint16_t* nxt = (t & 1) ? lds0 : lds1;

        float xv[8];
        if (t + 1 < 8) {
            const float* sB = srcB + (size_t)(t+1)*32*D_;
            #pragma unroll
            for (int i = 0; i < 8; ++i) xv[i] = sB[i * D_];
            #pragma unroll
            for (int i = 0; i < 4; ++i)
                gload_lds16(srcA[i] + (t+1)*32, &nxt[(w*4 + i) * 512]);
        }

        s16x8 bf[4];
        #pragma unroll
        for (int nt = 0; nt < 4; ++nt)
            bf[nt] = *(const s16x8*)&cur[(16 + nt) * 512 + lane*8];
        #pragma unroll
        for (int m = 0; m < 4; ++m) {
            const s16x8 af = *(const s16x8*)&cur[(w*4 + m) * 512 + lane*8];
            #pragma unroll
            for (int nt = 0; nt < 4; ++nt)
                acc[m][nt] = __builtin_amdgcn_mfma_f32_16x16x32_bf16(af, bf[nt], acc[m][nt], 0, 0, 0);
        }

        if (t + 1 < 8) {
            s16x8 h;
            #pragma unroll
            for (int i = 0; i < 8; ++i) h[i] = (short)f2bf(xv[i]);
            *(s16x8*)&nxt[boff] = h;
        }
        __syncthreads();
    }

    // ---- epilogue: bf16-pair dword stores, [d][kk] layout.
    // lane holds 4 consecutive kk (r=0..3) at fixed d = nt*16+l16.
    #pragma unroll
    for (int m = 0; m < 4; ++m) {
        const int kkrow = w*64 + m*16 + grp*4;
        #pragma unroll
        for (int nt = 0; nt < 4; ++nt) {
            const int didx = nt*16 + l16;
            outp[didx*128 + (kkrow >> 1)]     = pk2(acc[m][nt][0], acc[m][nt][1]);
            outp[didx*128 + (kkrow >> 1) + 1] = pk2(acc[m][nt][2], acc[m][nt][3]);
        }
    }
}

// ---------------------------------------------------------------------------
// bias_reduce: sum 16 bf16-pair split-K partials + bias, cvt to bf16.
// V: [d][kk] layout passes straight through (coalesced u32 writes).
// K: transposed to [kk][d] via padded LDS tile.
// grid = 32 b * 4 dt = 128 blocks, 256 threads; tile = 16 d x 256 kk.
// ---------------------------------------------------------------------------
__global__ __launch_bounds__(256) void bias_reduce(
        const uint32_t* __restrict__ part, const float* __restrict__ E_b,
        uint16_t* __restrict__ Kbf, uint16_t* __restrict__ Vbf) {
    const int b  = blockIdx.x >> 2;
    const int dt = blockIdx.x & 3;
    const int t  = threadIdx.x;

    __shared__ uint16_t Kt[256][18];   // [kk][d_l], padded

    const uint32_t* Kp = part + ((size_t)(b*16))      * 8192 + dt*16*128;
    const uint32_t* Vp = part + ((size_t)((32+b)*16)) * 8192 + dt*16*128;

    #pragma unroll
    for (int j = 0; j < 8; ++j) {
        const int idx = j*256 + t;
        const int d_l = idx >> 7;      // 0..15
        const int kkp = idx & 127;     // 0..127
        float k0 = 0.f, k1 = 0.f, v0 = 0.f, v1 = 0.f;
        #pragma unroll
        for (int s = 0; s < 16; ++s) {
            const uint32_t ku = Kp[(size_t)s*8192 + d_l*128 + kkp];
            const uint32_t vu = Vp[(size_t)s*8192 + d_l*128 + kkp];
            k0 += bf2f(ku << 16);
            k1 += bf2f(ku & 0xffff0000u);
            v0 += bf2f(vu << 16);
            v1 += bf2f(vu & 0xffff0000u);
        }
        const int kk0 = kkp*2;
        const float b0 = E_b[kk0], b1 = E_b[kk0 + 1];
        *(uint32_t*)(Vbf + ((size_t)(b*64 + dt*16 + d_l))*256 + kk0) =
            (uint32_t)f2bf(v0 + b0) | ((uint32_t)f2bf(v1 + b1) << 16);
        Kt[kk0][d_l]     = f2bf(k0 + b0);
        Kt[kk0 + 1][d_l] = f2bf(k1 + b1);
    }
    __syncthreads();

    // K transposed write: thread t = kk row, 16 d values
    uint16_t* kout = Kbf + ((size_t)(b*256 + t))*64 + dt*16;
    s16x8 o0, o1;
    #pragma unroll
    for (int i = 0; i < 8; ++i) {
        o0[i] = (short)Kt[t][i];
        o1[i] = (short)Kt[t][8 + i];
    }
    *(s16x8*)kout       = o0;
    *(s16x8*)(kout + 8) = o1;
}

// ---------------------------------------------------------------------------
// attn v6 (unchanged, verified): K/V staged once per block into LDS in
// fragment order; 8 waves x 16 rows; no-max softmax; shfl P-exchange.
// grid = 32 b * 32 tiles = 1024 blocks, 512 threads.
// ---------------------------------------------------------------------------
__global__ __launch_bounds__(512, 4) void attn(
        const float* __restrict__ q,
        const uint16_t* __restrict__ Kbf, const uint16_t* __restrict__ Vbf,
        float* __restrict__ out) {
    const int wg   = blockIdx.x;
    const int st   = wg & 31;
    const int b    = wg >> 5;
    const int tid  = threadIdx.x;
    const int wave = tid >> 6;
    const int lane = tid & 63;
    const int l16  = lane & 15;
    const int grp  = lane >> 4;
    const int s0   = st * 128 + wave * 16;

    __shared__ __align__(16) uint16_t Klds[16384];
    __shared__ __align__(16) uint16_t Vlds[16384];

    const uint16_t* Kb = Kbf + (size_t)b * DK_ * D_;
    const uint16_t* Vb = Vbf + (size_t)b * D_ * DK_;

    #pragma unroll
    for (int i = 0; i < 4; ++i) {
        const int s  = wave*4 + i;
        const int nt = s >> 1, kt = s & 1;
        gload_lds16(Kb + (size_t)(nt*16 + l16) * D_ + kt*32 + grp*8, &Klds[s*512]);
    }
    #pragma unroll
    for (int i = 0; i < 4; ++i) {
        const int s   = wave*4 + i;
        const int kt2 = s >> 2, nt2 = s & 3;
        gload_lds16(Vb + (size_t)(nt2*16 + l16) * DK_ + kt2*32 + grp*8, &Vlds[s*512]);
    }

    s16x8 qb[2];
    {
        const float* qp = q + ((size_t)b * S_ + s0 + l16) * D_;
        #pragma unroll
        for (int kt = 0; kt < 2; ++kt) {
            const int d0 = kt*32 + grp*8;
            const float4 f0 = *(const float4*)(qp + d0);
            const float4 f1 = *(const float4*)(qp + d0 + 4);
            s16x8 a;
            a[0] = (short)f2bf(f0.x * 0.125f);
            a[1] = (short)f2bf(f0.y * 0.125f);
            a[2] = (short)f2bf(f0.z * 0.125f);
            a[3] = (short)f2bf(f0.w * 0.125f);
            a[4] = (short)f2bf(f1.x * 0.125f);
            a[5] = (short)f2bf(f1.y * 0.125f);
            a[6] = (short)f2bf(f1.z * 0.125f);
            a[7] = (short)f2bf(f1.w * 0.125f);
            qb[kt] = a;
        }
    }

    __syncthreads();

    f32x4 acc[16] = {};
    #pragma unroll
    for (int nt = 0; nt < 16; ++nt) {
        #pragma unroll
        for (int kt = 0; kt < 2; ++kt) {
            const s16x8 kf = *(const s16x8*)&Klds[(nt*2 + kt)*512 + lane*8];
            acc[nt] = __builtin_amdgcn_mfma_f32_16x16x32_bf16(kf, qb[kt], acc[nt], 0, 0, 0);
        }
    }

    float sm = 0.f;
    #pragma unroll
    for (int nt = 0; nt < 16; ++nt) {
        #pragma unroll
        for (int r = 0; r < 4; ++r) {
            const float e = __expf(acc[nt][r]);
            acc[nt][r] = e;
            sm += e;
        }
    }
    sm += __shfl_xor(sm, 16);
    sm += __shfl_xor(sm, 32);
    const float inv = 1.f / sm;

    uint32_t pk[16][2];
    #pragma unroll
    for (int nt = 0; nt < 16; ++nt) {
        pk[nt][0] = pk2(acc[nt][0], acc[nt][1]);
        pk[nt][1] = pk2(acc[nt][2], acc[nt][3]);
    }

    float invs[4];
    #pragma unroll
    for (int r = 0; r < 4; ++r) invs[r] = __shfl(inv, grp*4 + r);

    const int sl0 = (((grp << 1) + 0) & 3) * 16 + l16;
    const int sl1 = (((grp << 1) + 1) & 3) * 16 + l16;
    const bool lohalf = (grp < 2);

    f32x4 o[4] = {};
    #pragma unroll
    for (int kt2 = 0; kt2 < 8; ++kt2) {
        union { u32x4 wv; s16x8 h; } u;
        #pragma unroll
        for (int c = 0; c < 4; ++c) {
            const int tt = c & 1;
            const int sl = (c >> 1) ? sl1 : sl0;
            const uint32_t lo = (uint32_t)__shfl((int)pk[2*kt2 + 0][tt], sl);
            const uint32_t hi = (uint32_t)__shfl((int)pk[2*kt2 + 1][tt], sl);
            u.wv[c] = lohalf ? lo : hi;
        }
        #pragma unroll
        for (int nt2 = 0; nt2 < 4; ++nt2) {
            const s16x8 vf = *(const s16x8*)&Vlds[(kt2*4 + nt2)*512 + lane*8];
            o[nt2] = __builtin_amdgcn_mfma_f32_16x16x32_bf16(u.h, vf, o[nt2], 0, 0, 0);
        }
    }

    #pragma unroll
    for (int nt2 = 0; nt2 < 4; ++nt2)
        #pragma unroll
        for (int r = 0; r < 4; ++r)
            out[((size_t)b * S_ + s0 + grp*4 + r) * D_ + nt2*16 + l16] =
                o[nt2][r] * invs[r];
}

extern "C" void kernel_launch(void* const* d_in, const int* in_sizes, int n_in,
                              void* d_out, int out_size, void* d_ws, size_t ws_size,
                              hipStream_t stream) {
    const float* q   = (const float*)d_in[0];
    const float* k   = (const float*)d_in[1];
    const float* v   = (const float*)d_in[2];
    const float* E_w = (const float*)d_in[3];
    const float* E_b = (const float*)d_in[4];
    float* out = (float*)d_out;

    char* ws = (char*)d_ws;
    uint32_t* part = (uint32_t*)(ws);                     // 32 MB bf16-pairs
    uint16_t* Kbf  = (uint16_t*)(ws + (32u << 20));       // 1 MB
    uint16_t* Vbf  = (uint16_t*)(ws + (33u << 20));       // 1 MB
    uint16_t* Ewb  = (uint16_t*)(ws + (34u << 20));       // 2 MB

    ewcvt<<<512, 256, 0, stream>>>(E_w, Ewb);
    proj_mfma<<<1024, 256, 0, stream>>>(Ewb, k, v, part);
    bias_reduce<<<128, 256, 0, stream>>>(part, E_b, Kbf, Vbf);
    attn<<<1024, 512, 0, stream>>>(q, Kbf, Vbf, out);
}

// Round 10
// 64.820 us; speedup vs baseline: 1.1121x; 1.1121x over previous
//
#include <hip/hip_runtime.h>
#include <hip/hip_bf16.h>
#include <stdint.h>

#define B_  32
#define S_  4096
#define D_  64
#define DK_ 256

typedef float f32x4 __attribute__((ext_vector_type(4)));
typedef short s16x8 __attribute__((ext_vector_type(8)));
typedef uint32_t u32x4 __attribute__((ext_vector_type(4)));

static __device__ __forceinline__ uint16_t f2bf(float f) {
    union { float f; uint32_t u; } x; x.f = f;
    uint32_t u = x.u;
    u += 0x7FFFu + ((u >> 16) & 1u);   // RNE
    return (uint16_t)(u >> 16);
}

static __device__ __forceinline__ float bf2f(uint32_t hi16) {
    union { uint32_t u; float f; } x; x.u = hi16;
    return x.f;
}

static __device__ __forceinline__ uint32_t pk2(float a, float b) {
    __hip_bfloat162 h = __float22bfloat162_rn(float2{a, b});
    union { __hip_bfloat162 h; uint32_t u; } c; c.h = h;
    return c.u;
}

static __device__ __forceinline__ void gload_lds16(const uint16_t* g, uint16_t* l) {
    __builtin_amdgcn_global_load_lds(
        (const __attribute__((address_space(1))) uint32_t*)g,
        (__attribute__((address_space(3))) uint32_t*)l, 16, 0, 0);
}

// ---------------------------------------------------------------------------
// Pass A1: E_w fp32 -> bf16, PRE-SWIZZLED into proj's fragment order:
// EwbS[kktile(16)][schunk(128)][lane(64)][e(8)], where
//   kk = kktile*16 + (lane&15), s = schunk*32 + (lane>>4)*8 + e.
// Proj staging then reads 1 KB CONTIGUOUS per global_load_lds (lane*16B),
// killing the 16-segment scatter that choked R8/R9.
// ---------------------------------------------------------------------------
__global__ __launch_bounds__(256) void ewcvt(const float* __restrict__ E_w,
                                             uint16_t* __restrict__ EwbS) {
    const int tg     = blockIdx.x * 256 + threadIdx.x;   // 0..131071
    const int l16    = tg & 15;
    const int grp    = (tg >> 4) & 3;
    const int schunk = (tg >> 6) & 127;
    const int kktile = tg >> 13;
    const int kk = kktile*16 + l16;
    const int s  = schunk*32 + grp*8;
    const float4 f0 = *(const float4*)(E_w + (size_t)kk * S_ + s);
    const float4 f1 = *(const float4*)(E_w + (size_t)kk * S_ + s + 4);
    s16x8 o;
    o[0] = (short)f2bf(f0.x); o[1] = (short)f2bf(f0.y);
    o[2] = (short)f2bf(f0.z); o[3] = (short)f2bf(f0.w);
    o[4] = (short)f2bf(f1.x); o[5] = (short)f2bf(f1.y);
    o[6] = (short)f2bf(f1.z); o[7] = (short)f2bf(f1.w);
    *(s16x8*)(EwbS + (size_t)tg * 8) = o;
}

// ---------------------------------------------------------------------------
// Pass B: projection GEMM. ss split = 16, 8 K-iterations, 2-phase double
// buffer; A staged via CONTIGUOUS 1KB global_load_lds from EwbS; fused
// transpose+cvt of x; bf16-pair partials in [d][kk] layout.
// part_u32[r][d][kkp]: r = (p*32+b)*16+ss, kkp = kk/2.
// ---------------------------------------------------------------------------
__global__ __launch_bounds__(256, 4) void proj_mfma(
        const uint16_t* __restrict__ EwbS,
        const float* __restrict__ kin, const float* __restrict__ vin,
        uint32_t* __restrict__ part) {
    const int bid = blockIdx.x;
    const int ss = bid & 15;
    const int b  = (bid >> 4) & 31;
    const int p  = bid >> 9;
    const float* x = (p ? vin : kin) + (size_t)b * S_ * D_;
    uint32_t* outp = part + ((size_t)((p*32 + b)*16 + ss)) * 8192;

    __shared__ __align__(16) uint16_t lds0[20 * 512];   // 20 KB
    __shared__ __align__(16) uint16_t lds1[20 * 512];   // 20 KB

    const int tid  = threadIdx.x;
    const int w    = tid >> 6;
    const int lane = tid & 63;
    const int l16  = lane & 15;
    const int grp  = lane >> 4;

    // A sources: fragment-order EwbS; chunk (kktile = w*4+i, schunk = ss*8+t);
    // per-lane = chunk_base + lane*8 elems -> contiguous 1KB per instruction.
    const uint16_t* srcA[4];
    #pragma unroll
    for (int i = 0; i < 4; ++i)
        srcA[i] = EwbS + ((((size_t)(w*4 + i))*128 + ss*8) << 9) + lane*8;

    // B source (fp32 x, [s][d]): thread owns column d = tid&63, rows w*8..+7
    const int dcol = tid & 63;
    const float* srcB = x + ((size_t)(ss*256 + w*8)) * D_ + dcol;
    const int boff = 16*512 + (dcol >> 4)*512 + (w*16 + (dcol & 15))*8;

    f32x4 acc[4][4] = {};

    // ---- prologue: stage tile 0 into lds0
    {
        float xv[8];
        #pragma unroll
        for (int i = 0; i < 8; ++i) xv[i] = srcB[i * D_];
        #pragma unroll
        for (int i = 0; i < 4; ++i)
            gload_lds16(srcA[i], &lds0[(w*4 + i) * 512]);
        s16x8 h;
        #pragma unroll
        for (int i = 0; i < 8; ++i) h[i] = (short)f2bf(xv[i]);
        *(s16x8*)&lds0[boff] = h;
    }
    __syncthreads();

    // ---- 2-phase main loop: STAGE(t+1) issued before compute(t)
    #pragma unroll
    for (int t = 0; t < 8; ++t) {
        uint16_t* cur = (t & 1) ? lds1 : lds0;
        uint16_t* nxt = (t & 1) ? lds0 : lds1;

        float xv[8];
        if (t + 1 < 8) {
            const float* sB = srcB + (size_t)(t+1)*32*D_;
            #pragma unroll
            for (int i = 0; i < 8; ++i) xv[i] = sB[i * D_];
            #pragma unroll
            for (int i = 0; i < 4; ++i)
                gload_lds16(srcA[i] + (t+1)*512, &nxt[(w*4 + i) * 512]);
        }

        s16x8 bf[4];
        #pragma unroll
        for (int nt = 0; nt < 4; ++nt)
            bf[nt] = *(const s16x8*)&cur[(16 + nt) * 512 + lane*8];
        #pragma unroll
        for (int m = 0; m < 4; ++m) {
            const s16x8 af = *(const s16x8*)&cur[(w*4 + m) * 512 + lane*8];
            #pragma unroll
            for (int nt = 0; nt < 4; ++nt)
                acc[m][nt] = __builtin_amdgcn_mfma_f32_16x16x32_bf16(af, bf[nt], acc[m][nt], 0, 0, 0);
        }

        if (t + 1 < 8) {
            s16x8 h;
            #pragma unroll
            for (int i = 0; i < 8; ++i) h[i] = (short)f2bf(xv[i]);
            *(s16x8*)&nxt[boff] = h;
        }
        __syncthreads();
    }

    // ---- epilogue: bf16-pair dword stores, [d][kk] layout.
    #pragma unroll
    for (int m = 0; m < 4; ++m) {
        const int kkrow = w*64 + m*16 + grp*4;
        #pragma unroll
        for (int nt = 0; nt < 4; ++nt) {
            const int didx = nt*16 + l16;
            outp[didx*128 + (kkrow >> 1)]     = pk2(acc[m][nt][0], acc[m][nt][1]);
            outp[didx*128 + (kkrow >> 1) + 1] = pk2(acc[m][nt][2], acc[m][nt][3]);
        }
    }
}

// ---------------------------------------------------------------------------
// bias_reduce (unchanged from R9, verified): sum 16 bf16-pair partials + bias.
// V passes straight through ([d][kk]); K transposed via padded LDS tile.
// ---------------------------------------------------------------------------
__global__ __launch_bounds__(256) void bias_reduce(
        const uint32_t* __restrict__ part, const float* __restrict__ E_b,
        uint16_t* __restrict__ Kbf, uint16_t* __restrict__ Vbf) {
    const int b  = blockIdx.x >> 2;
    const int dt = blockIdx.x & 3;
    const int t  = threadIdx.x;

    __shared__ uint16_t Kt[256][18];

    const uint32_t* Kp = part + ((size_t)(b*16))      * 8192 + dt*16*128;
    const uint32_t* Vp = part + ((size_t)((32+b)*16)) * 8192 + dt*16*128;

    #pragma unroll
    for (int j = 0; j < 8; ++j) {
        const int idx = j*256 + t;
        const int d_l = idx >> 7;
        const int kkp = idx & 127;
        float k0 = 0.f, k1 = 0.f, v0 = 0.f, v1 = 0.f;
        #pragma unroll
        for (int s = 0; s < 16; ++s) {
            const uint32_t ku = Kp[(size_t)s*8192 + d_l*128 + kkp];
            const uint32_t vu = Vp[(size_t)s*8192 + d_l*128 + kkp];
            k0 += bf2f(ku << 16);
            k1 += bf2f(ku & 0xffff0000u);
            v0 += bf2f(vu << 16);
            v1 += bf2f(vu & 0xffff0000u);
        }
        const int kk0 = kkp*2;
        const float b0 = E_b[kk0], b1 = E_b[kk0 + 1];
        *(uint32_t*)(Vbf + ((size_t)(b*64 + dt*16 + d_l))*256 + kk0) =
            (uint32_t)f2bf(v0 + b0) | ((uint32_t)f2bf(v1 + b1) << 16);
        Kt[kk0][d_l]     = f2bf(k0 + b0);
        Kt[kk0 + 1][d_l] = f2bf(k1 + b1);
    }
    __syncthreads();

    uint16_t* kout = Kbf + ((size_t)(b*256 + t))*64 + dt*16;
    s16x8 o0, o1;
    #pragma unroll
    for (int i = 0; i < 8; ++i) {
        o0[i] = (short)Kt[t][i];
        o1[i] = (short)Kt[t][8 + i];
    }
    *(s16x8*)kout       = o0;
    *(s16x8*)(kout + 8) = o1;
}

// ---------------------------------------------------------------------------
// attn v6 (unchanged, verified).
// ---------------------------------------------------------------------------
__global__ __launch_bounds__(512, 4) void attn(
        const float* __restrict__ q,
        const uint16_t* __restrict__ Kbf, const uint16_t* __restrict__ Vbf,
        float* __restrict__ out) {
    const int wg   = blockIdx.x;
    const int st   = wg & 31;
    const int b    = wg >> 5;
    const int tid  = threadIdx.x;
    const int wave = tid >> 6;
    const int lane = tid & 63;
    const int l16  = lane & 15;
    const int grp  = lane >> 4;
    const int s0   = st * 128 + wave * 16;

    __shared__ __align__(16) uint16_t Klds[16384];
    __shared__ __align__(16) uint16_t Vlds[16384];

    const uint16_t* Kb = Kbf + (size_t)b * DK_ * D_;
    const uint16_t* Vb = Vbf + (size_t)b * D_ * DK_;

    #pragma unroll
    for (int i = 0; i < 4; ++i) {
        const int s  = wave*4 + i;
        const int nt = s >> 1, kt = s & 1;
        gload_lds16(Kb + (size_t)(nt*16 + l16) * D_ + kt*32 + grp*8, &Klds[s*512]);
    }
    #pragma unroll
    for (int i = 0; i < 4; ++i) {
        const int s   = wave*4 + i;
        const int kt2 = s >> 2, nt2 = s & 3;
        gload_lds16(Vb + (size_t)(nt2*16 + l16) * DK_ + kt2*32 + grp*8, &Vlds[s*512]);
    }

    s16x8 qb[2];
    {
        const float* qp = q + ((size_t)b * S_ + s0 + l16) * D_;
        #pragma unroll
        for (int kt = 0; kt < 2; ++kt) {
            const int d0 = kt*32 + grp*8;
            const float4 f0 = *(const float4*)(qp + d0);
            const float4 f1 = *(const float4*)(qp + d0 + 4);
            s16x8 a;
            a[0] = (short)f2bf(f0.x * 0.125f);
            a[1] = (short)f2bf(f0.y * 0.125f);
            a[2] = (short)f2bf(f0.z * 0.125f);
            a[3] = (short)f2bf(f0.w * 0.125f);
            a[4] = (short)f2bf(f1.x * 0.125f);
            a[5] = (short)f2bf(f1.y * 0.125f);
            a[6] = (short)f2bf(f1.z * 0.125f);
            a[7] = (short)f2bf(f1.w * 0.125f);
            qb[kt] = a;
        }
    }

    __syncthreads();

    f32x4 acc[16] = {};
    #pragma unroll
    for (int nt = 0; nt < 16; ++nt) {
        #pragma unroll
        for (int kt = 0; kt < 2; ++kt) {
            const s16x8 kf = *(const s16x8*)&Klds[(nt*2 + kt)*512 + lane*8];
            acc[nt] = __builtin_amdgcn_mfma_f32_16x16x32_bf16(kf, qb[kt], acc[nt], 0, 0, 0);
        }
    }

    float sm = 0.f;
    #pragma unroll
    for (int nt = 0; nt < 16; ++nt) {
        #pragma unroll
        for (int r = 0; r < 4; ++r) {
            const float e = __expf(acc[nt][r]);
            acc[nt][r] = e;
            sm += e;
        }
    }
    sm += __shfl_xor(sm, 16);
    sm += __shfl_xor(sm, 32);
    const float inv = 1.f / sm;

    uint32_t pk[16][2];
    #pragma unroll
    for (int nt = 0; nt < 16; ++nt) {
        pk[nt][0] = pk2(acc[nt][0], acc[nt][1]);
        pk[nt][1] = pk2(acc[nt][2], acc[nt][3]);
    }

    float invs[4];
    #pragma unroll
    for (int r = 0; r < 4; ++r) invs[r] = __shfl(inv, grp*4 + r);

    const int sl0 = (((grp << 1) + 0) & 3) * 16 + l16;
    const int sl1 = (((grp << 1) + 1) & 3) * 16 + l16;
    const bool lohalf = (grp < 2);

    f32x4 o[4] = {};
    #pragma unroll
    for (int kt2 = 0; kt2 < 8; ++kt2) {
        union { u32x4 wv; s16x8 h; } u;
        #pragma unroll
        for (int c = 0; c < 4; ++c) {
            const int tt = c & 1;
            const int sl = (c >> 1) ? sl1 : sl0;
            const uint32_t lo = (uint32_t)__shfl((int)pk[2*kt2 + 0][tt], sl);
            const uint32_t hi = (uint32_t)__shfl((int)pk[2*kt2 + 1][tt], sl);
            u.wv[c] = lohalf ? lo : hi;
        }
        #pragma unroll
        for (int nt2 = 0; nt2 < 4; ++nt2) {
            const s16x8 vf = *(const s16x8*)&Vlds[(kt2*4 + nt2)*512 + lane*8];
            o[nt2] = __builtin_amdgcn_mfma_f32_16x16x32_bf16(u.h, vf, o[nt2], 0, 0, 0);
        }
    }

    #pragma unroll
    for (int nt2 = 0; nt2 < 4; ++nt2)
        #pragma unroll
        for (int r = 0; r < 4; ++r)
            out[((size_t)b * S_ + s0 + grp*4 + r) * D_ + nt2*16 + l16] =
                o[nt2][r] * invs[r];
}

extern "C" void kernel_launch(void* const* d_in, const int* in_sizes, int n_in,
                              void* d_out, int out_size, void* d_ws, size_t ws_size,
                              hipStream_t stream) {
    const float* q   = (const float*)d_in[0];
    const float* k   = (const float*)d_in[1];
    const float* v   = (const float*)d_in[2];
    const float* E_w = (const float*)d_in[3];
    const float* E_b = (const float*)d_in[4];
    float* out = (float*)d_out;

    char* ws = (char*)d_ws;
    uint32_t* part = (uint32_t*)(ws);                     // 32 MB bf16-pairs
    uint16_t* Kbf  = (uint16_t*)(ws + (32u << 20));       // 1 MB
    uint16_t* Vbf  = (uint16_t*)(ws + (33u << 20));       // 1 MB
    uint16_t* EwbS = (uint16_t*)(ws + (34u << 20));       // 2 MB swizzled

    ewcvt<<<512, 256, 0, stream>>>(E_w, EwbS);
    proj_mfma<<<1024, 256, 0, stream>>>(EwbS, k, v, part);
    bias_reduce<<<128, 256, 0, stream>>>(part, E_b, Kbf, Vbf);
    attn<<<1024, 512, 0, stream>>>(q, Kbf, Vbf, out);
}